// Round 2
// baseline (3757.362 us; speedup 1.0000x reference)
//
#include <hip/hip_runtime.h>
#include <hip/hip_bf16.h>

#define NN 1024
#define BT 64          // tile size
#define TT 16          // tiles per dim

// ---------------------------------------------------------------------------
// primes[i] = BASE_PRIMES[argmax_ch feat[0, ch, i, 0]]  (first-max)
// ---------------------------------------------------------------------------
__global__ void primes_kernel(const float* __restrict__ feat, int* __restrict__ primes) {
    int i = blockIdx.x * blockDim.x + threadIdx.x;
    if (i < NN) {
        float best = feat[i * NN];
        int arg = 0;
        for (int ch = 1; ch < 4; ++ch) {
            float v = feat[ch * NN * NN + i * NN];
            if (v > best) { best = v; arg = ch; }
        }
        const int P[4] = {2, 3, 5, 7};
        primes[i] = P[arg];
    }
}

// ---------------------------------------------------------------------------
// S = premask(con); zero R, C, out
// ---------------------------------------------------------------------------
__global__ void prep_kernel(const float* __restrict__ con, const int* __restrict__ primes,
                            float* __restrict__ S, double* __restrict__ R,
                            double* __restrict__ C, float* __restrict__ out) {
    int idx = blockIdx.x * blockDim.x + threadIdx.x;
    int i = idx >> 10;
    int j = idx & (NN - 1);
    float c = (con[idx] + con[j * NN + i]) * 0.5f;
    int prod = primes[i] * primes[j];
    bool canon = (prod == 14) | (prod == 15) | (prod == 35);
    int d = i - j; if (d < 0) d = -d;
    S[idx] = (canon && d >= 4) ? c : 0.0f;
    R[idx] = 0.0;
    C[idx] = 0.0;
    out[idx] = 0.0f;
}

// ---------------------------------------------------------------------------
// dd=0: diagonal 64x64 tiles, fully in LDS. One workgroup per tile.
// ---------------------------------------------------------------------------
__global__ __launch_bounds__(256) void diag_tiles_kernel(double* __restrict__ R,
                                                         double* __restrict__ C,
                                                         const float* __restrict__ S) {
    __shared__ double VT[64][65];
    __shared__ float  SSt[64][64];
    int a = blockIdx.x * BT;
    int tid = threadIdx.x;
    for (int idx = tid; idx < 4096; idx += 256) {
        int r = idx >> 6, c = idx & 63;
        VT[r][c] = 0.0;
        SSt[r][c] = S[(a + r) * NN + a + c];
    }
    __syncthreads();
    int cell = tid >> 2, sub = tid & 3;
    for (int d = 1; d < 64; ++d) {
        int r = cell;
        if (r + d < 64) {
            int c = r + d;
            double acc = -1.0;
            for (int kk = r + sub; kk < c; kk += 4)
                acc = fmax(acc, VT[r][kk] + VT[kk + 1][c]);
            acc = fmax(acc, __shfl_xor(acc, 1));
            acc = fmax(acc, __shfl_xor(acc, 2));
            if (sub == 0) {
                // d==1: VT[r+1][r]=0 (below diag) -> pair = 0 + s, matches ref
                acc = fmax(acc, VT[r + 1][c - 1] + (double)SSt[r][c]);
                VT[r][c] = acc;
            }
        }
        __syncthreads();
    }
    for (int idx = tid; idx < 4096; idx += 256) {
        int r = idx >> 6, c = idx & 63;
        R[(a + r) * NN + a + c] = VT[r][c];
        C[(a + c) * NN + a + r] = VT[r][c];
    }
}

// ---------------------------------------------------------------------------
// Phase A: external split contributions for tile (I, J=I+dd), one block per
// (tile, interior k-tile). Max-plus 64x64x64 into Pbuf[blockIdx].
// P(i,j) = max_{k in ktile} R[i*N+k] + C[j*N+k+1]  (all operands final)
// ---------------------------------------------------------------------------
__global__ __launch_bounds__(256) void phaseA_kernel(const double* __restrict__ R,
                                                     const double* __restrict__ C,
                                                     double* __restrict__ Pbuf, int dd) {
    int nk = dd - 1;
    int t = blockIdx.x / nk;
    int kt = blockIdx.x - t * nk;
    int aI = t * BT;
    int aJ = (t + dd) * BT;
    int kb = (t + 1 + kt) * BT;
    __shared__ double Ast[64][65];   // Ast[kk][r] = V(aI+r, kb+kk)
    __shared__ double Bst[64][65];   // Bst[kk][c] = V(kb+kk+1, aJ+c)
    int tid = threadIdx.x;
    for (int idx = tid; idx < 4096; idx += 256) {
        int r = idx >> 6, kk = idx & 63;
        Ast[kk][r] = R[(aI + r) * NN + kb + kk];
        Bst[kk][r] = C[(aJ + r) * NN + kb + 1 + kk];
    }
    __syncthreads();
    int r4 = (tid >> 4) << 2;
    int c4 = (tid & 15) << 2;
    double acc[4][4];
    for (int x = 0; x < 4; ++x) for (int y = 0; y < 4; ++y) acc[x][y] = -1.0;
    for (int kk = 0; kk < 64; ++kk) {
        double av[4], bv[4];
        for (int x = 0; x < 4; ++x) av[x] = Ast[kk][r4 + x];
        for (int y = 0; y < 4; ++y) bv[y] = Bst[kk][c4 + y];
        for (int x = 0; x < 4; ++x)
            for (int y = 0; y < 4; ++y)
                acc[x][y] = fmax(acc[x][y], av[x] + bv[y]);
    }
    double* P = Pbuf + (size_t)blockIdx.x * 4096;
    for (int x = 0; x < 4; ++x)
        for (int y = 0; y < 4; ++y)
            P[(r4 + x) * 64 + c4 + y] = acc[x][y];
}

// ---------------------------------------------------------------------------
// Phase B: resolve intra-tile coupling for tile (I, J=I+dd). One workgroup
// per tile; 127 anti-diagonal micro-steps in LDS.
//  left  k in [i, bI]   : DII[r][kk] + VT(kk+1, c)   (kk=63 -> edgeRow)
//  right k+1 in [aJ, j] : VT(r, m-1) + DJJt[c][m]    (m=0  -> edgeCol)
//  pair  V(i+1, j-1) + s
// VTr/VTc are row/col-major copies so both scan directions are contiguous.
// ---------------------------------------------------------------------------
__global__ __launch_bounds__(256) void phaseB_kernel(double* __restrict__ R,
                                                     double* __restrict__ C,
                                                     const float* __restrict__ S,
                                                     const double* __restrict__ Pbuf, int dd) {
    __shared__ double DII[64][65];    // V(aI+r, aI+kk)
    __shared__ double DJJt[64][65];   // DJJt[c][m] = V(aJ+m, aJ+c)
    __shared__ double VTr[64][65];    // VTr[r][c] = V(aI+r, aJ+c) (init: P)
    __shared__ double VTc[64][65];    // VTc[c][r] = same, transposed
    __shared__ float  SSt[64][64];
    __shared__ double edgeRow[64];    // V(bI+1, aJ+c)
    __shared__ double edgeCol[64];    // V(aI+r, aJ-1)
    __shared__ double corner;         // V(bI+1, aJ-1)
    int t = blockIdx.x;
    int aI = t * BT, aJ = (t + dd) * BT;
    int tid = threadIdx.x;
    int nk = dd - 1;
    for (int idx = tid; idx < 4096; idx += 256) {
        int r = idx >> 6, c = idx & 63;
        DII[r][c]  = R[(aI + r) * NN + aI + c];
        DJJt[r][c] = C[(aJ + r) * NN + aJ + c];
        SSt[r][c]  = S[(aI + r) * NN + aJ + c];
        double p = -1.0;
        for (int q = 0; q < nk; ++q)
            p = fmax(p, Pbuf[(size_t)(t * nk + q) * 4096 + idx]);
        VTr[r][c] = p;
    }
    if (tid < 64) {
        edgeRow[tid] = R[(aI + 64) * NN + aJ + tid];
        edgeCol[tid] = C[(aJ - 1) * NN + aI + tid];
    }
    if (tid == 0) corner = C[(aJ - 1) * NN + aI + 64];
    __syncthreads();

    int cell = tid >> 2, sub = tid & 3;
    for (int step = 0; step < 127; ++step) {
        int off = step - 63;                 // c - r
        int r0 = off < 0 ? -off : 0;
        int r1 = off > 0 ? 63 - off : 63;
        int r = r0 + cell;
        if (r <= r1) {
            int c = r + off;
            double acc = -1.0;
            for (int kk = r + sub; kk < 63; kk += 4)
                acc = fmax(acc, DII[r][kk] + VTc[c][kk + 1]);
            for (int m = 1 + sub; m <= c; m += 4)
                acc = fmax(acc, VTr[r][m - 1] + DJJt[c][m]);
            acc = fmax(acc, __shfl_xor(acc, 1));
            acc = fmax(acc, __shfl_xor(acc, 2));
            if (sub == 0) {
                acc = fmax(acc, DII[r][63] + edgeRow[c]);      // k = bI
                acc = fmax(acc, edgeCol[r] + DJJt[c][0]);      // k = aJ-1
                acc = fmax(acc, VTr[r][c]);                    // external P
                double pv;
                if (r < 63) pv = (c > 0) ? VTc[c - 1][r + 1] : edgeCol[r + 1];
                else        pv = (c > 0) ? edgeRow[c - 1] : corner;
                acc = fmax(acc, pv + (double)SSt[r][c]);
                VTr[r][c] = acc;
                VTc[c][r] = acc;
            }
        }
        __syncthreads();
    }

    for (int idx = tid; idx < 4096; idx += 256) {
        int r = idx >> 6, c = idx & 63;
        R[(aI + r) * NN + aJ + c] = VTr[r][c];
        C[(aJ + r) * NN + aI + c] = VTc[r][c];
    }
}

// ---------------------------------------------------------------------------
// Traceback. Stack entries carry v (removes one dependent load per event);
// the three remaining loads per event are independent (single latency).
// Block-wide first-max argmax for split events.
// ---------------------------------------------------------------------------
__global__ __launch_bounds__(256) void traceback_kernel(const double* __restrict__ R,
                                                        const double* __restrict__ C,
                                                        const float* __restrict__ S,
                                                        float* __restrict__ out) {
    __shared__ int stk_i[2048];
    __shared__ int stk_j[2048];
    __shared__ double stk_v[2048];
    __shared__ int sh_top, sh_ii, sh_jj, sh_cmd;
    __shared__ double sred_v[4];
    __shared__ int sred_k[4];
    const double eps = 1e-9;
    if (threadIdx.x == 0) {
        sh_top = 1; stk_i[0] = 0; stk_j[0] = NN - 1; stk_v[0] = R[NN - 1];
    }
    __syncthreads();
    while (true) {
        if (threadIdx.x == 0) {
            int cmd = -1, top = sh_top;
            while (top > 0) {
                int i = stk_i[--top];
                int j = stk_j[top];
                double v = stk_v[top];
                if (j <= i) continue;
                if (v <= eps) continue;
                double a = R[(i + 1) * NN + j];
                float sv = S[i * NN + j];
                double b = R[(i + 1) * NN + j - 1];      // 0 if below diag
                if (a >= v - eps) {
                    stk_i[top] = i + 1; stk_j[top] = j; stk_v[top] = a; ++top;
                } else if (sv > 0.0f && b + (double)sv >= v - eps) {
                    out[i * NN + j] = sv; out[j * NN + i] = sv;
                    stk_i[top] = i + 1; stk_j[top] = j - 1; stk_v[top] = b; ++top;
                } else {
                    sh_ii = i; sh_jj = j; cmd = 0; break;
                }
            }
            sh_top = top; sh_cmd = cmd;
        }
        __syncthreads();
        if (sh_cmd < 0) break;
        int i = sh_ii, j = sh_jj;
        double bv = -1.0; int bk = 0x7fffffff;
        for (int k = i + threadIdx.x; k < j; k += 256) {
            double tv = R[i * NN + k] + C[j * NN + k + 1];
            if (tv > bv) { bv = tv; bk = k; }
        }
        for (int off = 32; off; off >>= 1) {
            double ov = __shfl_down(bv, off);
            int   ok = __shfl_down(bk, off);
            if (ov > bv || (ov == bv && ok < bk)) { bv = ov; bk = ok; }
        }
        if ((threadIdx.x & 63) == 0) { sred_v[threadIdx.x >> 6] = bv; sred_k[threadIdx.x >> 6] = bk; }
        __syncthreads();
        if (threadIdx.x == 0) {
            double fv = sred_v[0]; int fk = sred_k[0];
            for (int w = 1; w < 4; ++w)
                if (sred_v[w] > fv || (sred_v[w] == fv && sred_k[w] < fk)) { fv = sred_v[w]; fk = sred_k[w]; }
            int top = sh_top;
            stk_i[top] = i;      stk_j[top] = fk; stk_v[top] = R[i * NN + fk];     ++top;
            stk_i[top] = fk + 1; stk_j[top] = j;  stk_v[top] = C[j * NN + fk + 1]; ++top;
            sh_top = top;
        }
        __syncthreads();
    }
}

// ---------------------------------------------------------------------------
extern "C" void kernel_launch(void* const* d_in, const int* in_sizes, int n_in,
                              void* d_out, int out_size, void* d_ws, size_t ws_size,
                              hipStream_t stream) {
    const float* con  = (const float*)d_in[0];
    const float* feat = (const float*)d_in[1];
    float* out = (float*)d_out;

    char* ws = (char*)d_ws;
    double* R      = (double*)(ws);
    double* C      = (double*)(ws + (size_t)8  * 1024 * 1024);
    float*  S      = (float*) (ws + (size_t)16 * 1024 * 1024);
    int*    primes = (int*)   (ws + (size_t)20 * 1024 * 1024);
    double* Pbuf   = (double*)(ws + (size_t)20 * 1024 * 1024 + 65536);  // <=1.75 MB

    primes_kernel<<<(NN + 255) / 256, 256, 0, stream>>>(feat, primes);
    prep_kernel<<<(NN * NN) / 256, 256, 0, stream>>>(con, primes, S, R, C, out);
    diag_tiles_kernel<<<TT, 256, 0, stream>>>(R, C, S);

    for (int dd = 1; dd < TT; ++dd) {
        if (dd >= 2)
            phaseA_kernel<<<(TT - dd) * (dd - 1), 256, 0, stream>>>(R, C, Pbuf, dd);
        phaseB_kernel<<<TT - dd, 256, 0, stream>>>(R, C, S, Pbuf, dd);
    }

    traceback_kernel<<<1, 256, 0, stream>>>(R, C, S, out);
}